// Round 3
// baseline (114.618 us; speedup 1.0000x reference)
//
#include <hip/hip_runtime.h>

// PositionalEmbedding: out[node, t*32 + j] = (child_pos(ancestor_t(node)) == j)
// N = 262144, n = 32, k = 16. Output float32 [N, 512] = 512 MiB.
// Write-bandwidth-bound. Two-phase: (1) pack ancestor codes -> d_ws (4 MiB),
// (2) pure streaming one-hot expand (fill-shaped store loop).

#define NN 32   // one-hot width (n)
#define KK 16   // ancestor depth (k)
#define NPB 256 // nodes per block in fallback / codes kernel

typedef float f32x4 __attribute__((ext_vector_type(4)));  // native vec for NT store

// ---- Kernel 1: walk 16-step parent chains, pack 16 code bytes per node ----
__global__ __launch_bounds__(256) void pe_codes(
    const int* __restrict__ parents,
    const int* __restrict__ child_pos,
    uint4* __restrict__ codes_out, int N)
{
    const int node = blockIdx.x * blockDim.x + threadIdx.x;
    if (node >= N) return;
    unsigned int packed[KK / 4];
    int cur = node;
    #pragma unroll
    for (int w = 0; w < KK / 4; ++w) {
        unsigned int u = 0;
        #pragma unroll
        for (int b = 0; b < 4; ++b) {
            int cp = child_pos[cur];                 // independent load
            unsigned int byte = (cp < NN) ? (unsigned int)cp : 0xFFu;
            u |= byte << (8 * b);
            cur = parents[cur];                      // dependent chain load
        }
        packed[w] = u;
    }
    codes_out[node] = make_uint4(packed[0], packed[1], packed[2], packed[3]);
}

// ---- Kernel 2: pure streaming expand. One byte load (L1/L2 hit, 8-lane
// shared) per 16 B stored; q4 is loop-invariant since stride % 8 == 0. ----
__global__ __launch_bounds__(256) void pe_expand(
    const unsigned char* __restrict__ codes,
    f32x4* __restrict__ out4, size_t total_f4)
{
    const size_t stride = (size_t)gridDim.x * blockDim.x;      // multiple of 8
    const size_t gid    = (size_t)blockIdx.x * blockDim.x + threadIdx.x;
    const int q4 = (int)(gid & 7) * 4;                         // invariant
    #pragma unroll 8
    for (size_t idx = gid; idx < total_f4; idx += stride) {
        const int code = codes[idx >> 3];
        f32x4 v;
        v.x = (code == q4    ) ? 1.0f : 0.0f;
        v.y = (code == q4 + 1) ? 1.0f : 0.0f;
        v.z = (code == q4 + 2) ? 1.0f : 0.0f;
        v.w = (code == q4 + 3) ? 1.0f : 0.0f;
        __builtin_nontemporal_store(v, &out4[idx]);
    }
}

// ---- Fallback: proven single-kernel path (R1, 114 us) if ws too small ----
__global__ __launch_bounds__(256, 8) void pe_kernel(
    const int* __restrict__ parents,
    const int* __restrict__ child_pos,
    float* __restrict__ out, int N)
{
    __shared__ unsigned char codes[NPB * KK];
    const int tid   = threadIdx.x;
    const int node0 = blockIdx.x * NPB;
    const int node  = node0 + tid;

    unsigned int packed[KK / 4];
    if (node < N) {
        int cur = node;
        #pragma unroll
        for (int w = 0; w < KK / 4; ++w) {
            unsigned int u = 0;
            #pragma unroll
            for (int b = 0; b < 4; ++b) {
                int cp = child_pos[cur];
                unsigned int byte = (cp < NN) ? (unsigned int)cp : 0xFFu;
                u |= byte << (8 * b);
                cur = parents[cur];
            }
            packed[w] = u;
        }
    } else {
        #pragma unroll
        for (int w = 0; w < KK / 4; ++w) packed[w] = 0xFFFFFFFFu;
    }
    *reinterpret_cast<uint4*>(&codes[tid * KK]) =
        make_uint4(packed[0], packed[1], packed[2], packed[3]);
    __syncthreads();

    const int t_seg = (tid >> 3) & 15;
    const int q4    = (tid & 7) * 4;
    const int hi    = tid >> 7;
    float4* out4 = reinterpret_cast<float4*>(out) + (size_t)node0 * (NN * KK / 4);

    #pragma unroll 4
    for (int iter = 0; iter < (NPB * KK * NN / 4) / 256; ++iter) {
        const int nl   = 2 * iter + hi;
        const int code = codes[nl * KK + t_seg];
        float4 v;
        v.x = (code == q4    ) ? 1.0f : 0.0f;
        v.y = (code == q4 + 1) ? 1.0f : 0.0f;
        v.z = (code == q4 + 2) ? 1.0f : 0.0f;
        v.w = (code == q4 + 3) ? 1.0f : 0.0f;
        if (node0 + nl < N)
            out4[(size_t)iter * 256 + tid] = v;
    }
}

extern "C" void kernel_launch(void* const* d_in, const int* in_sizes, int n_in,
                              void* d_out, int out_size, void* d_ws, size_t ws_size,
                              hipStream_t stream) {
    const int* parents   = (const int*)d_in[0];
    const int* child_pos = (const int*)d_in[1];
    float* out = (float*)d_out;

    const int N = in_sizes[0] - 1;                    // 262144

    if (ws_size >= (size_t)N * KK) {
        // Phase 1: pack codes into workspace (4 MiB)
        const int grid1 = (N + 255) / 256;
        pe_codes<<<grid1, 256, 0, stream>>>(parents, child_pos, (uint4*)d_ws, N);

        // Phase 2: pure streaming expand
        const size_t total_f4 = (size_t)N * (NN * KK / 4);     // 33,554,432
        pe_expand<<<2048, 256, 0, stream>>>(
            (const unsigned char*)d_ws, (f32x4*)out, total_f4);
    } else {
        const int grid = (N + NPB - 1) / NPB;
        pe_kernel<<<grid, 256, 0, stream>>>(parents, child_pos, out, N);
    }
}

// Round 4
// 113.650 us; speedup vs baseline: 1.0085x; 1.0085x over previous
//
#include <hip/hip_runtime.h>

// PositionalEmbedding: out[node, t*32 + j] = (child_pos(ancestor_t(node)) == j)
// N = 262144, n = 32, k = 16. Output float32 [N, 512] = 512 MiB.
// Write-BW-bound with a random-access ancestor chase on the side.
// R4: merge parents+child_pos into int2 (1 random line per chase step, not 2),
// then fused chase+expand (R1 store structure, plain stores).

#define NN 32   // one-hot width (n)
#define KK 16   // ancestor depth (k)
#define NPB 256 // nodes per block == threads per block

// ---- Kernel 0: merge the two 4B tables into one 8B table (halves the
// number of random L2 lines touched per chase step) ----
__global__ __launch_bounds__(256) void pe_merge(
    const int* __restrict__ parents,
    const int* __restrict__ child_pos,
    int2* __restrict__ comb, int Np1)
{
    const int i = blockIdx.x * 256 + threadIdx.x;
    if (i < Np1) comb[i] = make_int2(parents[i], child_pos[i]);
}

// ---- Kernel 1: fused chase + one-hot expand (R1 structure) ----
__global__ __launch_bounds__(256, 8) void pe_fused(
    const int2* __restrict__ comb,
    float* __restrict__ out, int N)
{
    __shared__ unsigned char codes[NPB * KK]; // 4 KiB

    const int tid   = threadIdx.x;
    const int node0 = blockIdx.x * NPB;
    const int node  = node0 + tid;

    // Phase A: 16-step chase; one random int2 load per step.
    unsigned int packed[KK / 4];
    if (node < N) {
        int cur = node;
        #pragma unroll
        for (int w = 0; w < KK / 4; ++w) {
            unsigned int u = 0;
            #pragma unroll
            for (int b = 0; b < 4; ++b) {
                const int2 pc = comb[cur];          // parent, child_pos in 1 line
                const unsigned int byte =
                    (pc.y < NN) ? (unsigned int)pc.y : 0xFFu;
                u |= byte << (8 * b);
                cur = pc.x;
            }
            packed[w] = u;
        }
    } else {
        #pragma unroll
        for (int w = 0; w < KK / 4; ++w) packed[w] = 0xFFFFFFFFu;
    }
    *reinterpret_cast<uint4*>(&codes[tid * KK]) =
        make_uint4(packed[0], packed[1], packed[2], packed[3]);
    __syncthreads();

    // Phase B: cooperative, fully-coalesced one-hot store loop (as R1).
    const int t_seg = (tid >> 3) & 15;
    const int q4    = (tid & 7) * 4;
    const int hi    = tid >> 7; // 0 or 1
    float4* out4 = reinterpret_cast<float4*>(out) + (size_t)node0 * (NN * KK / 4);

    #pragma unroll 4
    for (int iter = 0; iter < (NPB * KK * NN / 4) / 256; ++iter) { // 128 iters
        const int nl   = 2 * iter + hi;
        const int code = codes[nl * KK + t_seg];
        float4 v;
        v.x = (code == q4    ) ? 1.0f : 0.0f;
        v.y = (code == q4 + 1) ? 1.0f : 0.0f;
        v.z = (code == q4 + 2) ? 1.0f : 0.0f;
        v.w = (code == q4 + 3) ? 1.0f : 0.0f;
        if (node0 + nl < N)
            out4[(size_t)iter * 256 + tid] = v;
    }
}

// ---- Fallback: proven single-kernel path (R1, 114 us) if ws too small ----
__global__ __launch_bounds__(256, 8) void pe_kernel(
    const int* __restrict__ parents,
    const int* __restrict__ child_pos,
    float* __restrict__ out, int N)
{
    __shared__ unsigned char codes[NPB * KK];
    const int tid   = threadIdx.x;
    const int node0 = blockIdx.x * NPB;
    const int node  = node0 + tid;

    unsigned int packed[KK / 4];
    if (node < N) {
        int cur = node;
        #pragma unroll
        for (int w = 0; w < KK / 4; ++w) {
            unsigned int u = 0;
            #pragma unroll
            for (int b = 0; b < 4; ++b) {
                int cp = child_pos[cur];
                unsigned int byte = (cp < NN) ? (unsigned int)cp : 0xFFu;
                u |= byte << (8 * b);
                cur = parents[cur];
            }
            packed[w] = u;
        }
    } else {
        #pragma unroll
        for (int w = 0; w < KK / 4; ++w) packed[w] = 0xFFFFFFFFu;
    }
    *reinterpret_cast<uint4*>(&codes[tid * KK]) =
        make_uint4(packed[0], packed[1], packed[2], packed[3]);
    __syncthreads();

    const int t_seg = (tid >> 3) & 15;
    const int q4    = (tid & 7) * 4;
    const int hi    = tid >> 7;
    float4* out4 = reinterpret_cast<float4*>(out) + (size_t)node0 * (NN * KK / 4);

    #pragma unroll 4
    for (int iter = 0; iter < (NPB * KK * NN / 4) / 256; ++iter) {
        const int nl   = 2 * iter + hi;
        const int code = codes[nl * KK + t_seg];
        float4 v;
        v.x = (code == q4    ) ? 1.0f : 0.0f;
        v.y = (code == q4 + 1) ? 1.0f : 0.0f;
        v.z = (code == q4 + 2) ? 1.0f : 0.0f;
        v.w = (code == q4 + 3) ? 1.0f : 0.0f;
        if (node0 + nl < N)
            out4[(size_t)iter * 256 + tid] = v;
    }
}

extern "C" void kernel_launch(void* const* d_in, const int* in_sizes, int n_in,
                              void* d_out, int out_size, void* d_ws, size_t ws_size,
                              hipStream_t stream) {
    const int* parents   = (const int*)d_in[0];
    const int* child_pos = (const int*)d_in[1];
    float* out = (float*)d_out;

    const int N   = in_sizes[0] - 1;              // 262144
    const int Np1 = N + 1;

    if (ws_size >= (size_t)Np1 * sizeof(int2)) {
        pe_merge<<<(Np1 + 255) / 256, 256, 0, stream>>>(
            parents, child_pos, (int2*)d_ws, Np1);
        pe_fused<<<(N + NPB - 1) / NPB, 256, 0, stream>>>(
            (const int2*)d_ws, out, N);
    } else {
        pe_kernel<<<(N + NPB - 1) / NPB, 256, 0, stream>>>(
            parents, child_pos, out, N);
    }
}